// Round 14
// baseline (119.321 us; speedup 1.0000x reference)
//
#include <hip/hip_runtime.h>

typedef _Float16 half8 __attribute__((ext_vector_type(8)));
typedef _Float16 half4v __attribute__((ext_vector_type(4)));
typedef __fp16  fp16x2 __attribute__((ext_vector_type(2)));   // cvt_pkrtz native type
typedef float   float4v __attribute__((ext_vector_type(4)));

#define S_LEN 4096
#define NBATCH 4
#define NCHUNK 4          // K-split factor: each chunk covers S/NCHUNK keys
// ws layout in halves:
//   W16  @ 0        : 256*128      = 32768
//   Qh   @ 32768    : 16384*64     = 1048576   (token-major [B*S][64], PRE-SCALED
//                     by 0.125*log2e so softmax is p = exp2(sc) with no fma)
//   Kh   @ 1081344  : 16384*64     = 1048576
//   Vt   @ 2129920  : 4*128*4096   = 2097152   (per-batch [128][S], PERMUTED per
//                     64-key tile: key k=grp*32+g*16+q*4+r stored at grp*32+q*8+g*4+r)
//   L    @ 4227072  : 16384 floats (fallback path accumulators)
// staged-path extras (byte offsets from ws base):
//   OACC @ 8519680  : NCHUNK*4*4096*128 fp16 = 16 MB   (per-chunk partial O, HALF)
//   LACC @ ...      : NCHUNK*4*4096 fp32     = 256 KB  (per-chunk partial l)
#define WS_W16 0
#define WS_QH  32768
#define WS_KH  1081344
#define WS_VT  2129920
#define WS_L   4227072
#define OACC_BYTE_OFF 8519680ull
#define CHUNK_ELEMS (NBATCH * S_LEN * 128)                      // 2097152
#define LACC_BYTE_OFF (OACC_BYTE_OFF + (unsigned long long)NCHUNK * CHUNK_ELEMS * 2)
#define WS_NEED_BYTES (LACC_BYTE_OFF + (unsigned long long)NCHUNK * NBATCH * S_LEN * 4)

#define QSCALE 0.18033688011112042f   // 0.125 * log2(e)

// async global -> LDS, 16 bytes per lane (global_load_lds_dwordx4)
static __device__ __forceinline__ void gload16(const _Float16* g, _Float16* l) {
    __builtin_amdgcn_global_load_lds(
        (const __attribute__((address_space(1))) void*)g,
        (__attribute__((address_space(3))) void*)l, 16, 0, 0);
}

// ---------------- kernel 0a: convert weights fp32 -> fp16, packed [256][128] --
__global__ __launch_bounds__(256) void wcvt_kernel(const float* __restrict__ Wq,
                                                   const float* __restrict__ Wk,
                                                   const float* __restrict__ Wv,
                                                   _Float16* __restrict__ w16) {
    int i = blockIdx.x * 256 + threadIdx.x;   // 0..32767
    int row = i >> 7, col = i & 127;
    float v;
    if (row < 64)       v = Wq[row * 128 + col];
    else if (row < 128) v = Wk[(row - 64) * 128 + col];
    else                v = Wv[(row - 128) * 128 + col];
    w16[i] = (_Float16)v;
}

// ---------------- kernel 0b (FALLBACK only): zero out + lbuf ------------------
__global__ __launch_bounds__(256) void zero_kernel(float4v* __restrict__ out4,
                                                   float4v* __restrict__ l4) {
    int i = blockIdx.x * 256 + threadIdx.x;   // 0..524287
    out4[i] = (float4v){0.f, 0.f, 0.f, 0.f};
    if (i < 4096) l4[i] = (float4v){0.f, 0.f, 0.f, 0.f};
}

// ---------------- kernel 1: QKV projection via MFMA (r7-proven form) ----------
// grid 1024 blocks x 256 thr; block owns 16 tokens; wave w owns oc [w*64, +64):
//   wave 0 -> Q (pre-scaled by QSCALE), wave 1 -> K, waves 2,3 -> V.
__global__ __launch_bounds__(256) void qkv_proj_kernel(const float* __restrict__ x,
                                                       const _Float16* __restrict__ w16,
                                                       _Float16* __restrict__ Qh,
                                                       _Float16* __restrict__ Kh,
                                                       _Float16* __restrict__ Vt) {
    __shared__ _Float16 xs[16 * 136];   // 16 rows, stride 136 halves (pad 128->136)
    const int t = threadIdx.x;
    const int blk = blockIdx.x;
    const float* xb = x + (size_t)blk * 16 * 128;

    for (int it = 0; it < 2; ++it) {
        int i = t + it * 256;           // 0..511 float4
        int row = i >> 5, c4 = i & 31;
        float4v f = ((const float4v*)xb)[i];
        half4v h;
        h[0] = (_Float16)f[0]; h[1] = (_Float16)f[1];
        h[2] = (_Float16)f[2]; h[3] = (_Float16)f[3];
        *(half4v*)&xs[row * 136 + c4 * 4] = h;
    }
    __syncthreads();

    const int w = t >> 6, lane = t & 63, quad = lane >> 4, n16 = lane & 15;

    half8 a[4];
    for (int c = 0; c < 4; ++c)
        a[c] = *(const half8*)&xs[n16 * 136 + c * 32 + quad * 8];

    float4v acc[4];
    for (int nb = 0; nb < 4; ++nb) acc[nb] = (float4v){0.f, 0.f, 0.f, 0.f};

    for (int c = 0; c < 4; ++c) {
        for (int nb = 0; nb < 4; ++nb) {
            int oc = w * 64 + nb * 16 + n16;
            half8 bfr = *(const half8*)&w16[(size_t)oc * 128 + c * 32 + quad * 8];
            acc[nb] = __builtin_amdgcn_mfma_f32_16x16x32_f16(a[c], bfr, acc[nb], 0, 0, 0);
        }
    }

    const int token0 = blk * 16 + quad * 4;
    if (w == 0) {
        // Q pre-scaled: softmax in flash becomes p = exp2(sc), no fma/shift.
        // (The dropped shift constant cancels exactly in the O/l normalization.)
        for (int nb = 0; nb < 4; ++nb)
            for (int r = 0; r < 4; ++r)
                Qh[(size_t)(token0 + r) * 64 + nb * 16 + n16] =
                    (_Float16)(acc[nb][r] * QSCALE);
    } else if (w == 1) {
        for (int nb = 0; nb < 4; ++nb)
            for (int r = 0; r < 4; ++r)
                Kh[(size_t)(token0 + r) * 64 + nb * 16 + n16] = (_Float16)acc[nb][r];
    } else {
        // V store, PERMUTED within each 64-key tile so flash reads b128 frags:
        // key s = kt*64+grp*32+g*16+q*4+r  ->  pos = kt*64+grp*32+q*8+g*4+r
        const int bb = token0 >> 12, s0 = token0 & 4095;
        const int kt = s0 >> 6, k0 = s0 & 63;
        const int grp = k0 >> 5, k32 = k0 & 31;
        const int g = k32 >> 4, q = (k32 >> 2) & 3;
        const int off = kt * 64 + grp * 32 + q * 8 + g * 4;
        for (int nb = 0; nb < 4; ++nb) {
            const int vc = (w - 2) * 64 + nb * 16 + n16;
            half4v h;
            h[0] = (_Float16)acc[nb][0]; h[1] = (_Float16)acc[nb][1];
            h[2] = (_Float16)acc[nb][2]; h[3] = (_Float16)acc[nb][3];
            *(half4v*)&Vt[((size_t)bb * 128 + vc) * S_LEN + off] = h;
        }
    }
}

// ---------------- kernel 2: flash attention, K-split x4, 2 q-tiles/wave -------
// grid (S/128, NCHUNK, B), 256 threads.  r10/r13-proven structure:
// double-buffered LDS via global_load_lds DMA (linear dest, source pre-swizzle
// LDS(row,ch) <- global(row, ch^(row&7))); ONE vmcnt(0)+barrier per iteration;
// 0 bank conflicts; setprio around MFMA clusters; p = exp2(sc) (Q pre-scaled,
// shift cancels in O/l); row-sums via ones-MFMA; P -> f16 via v_cvt_pkrtz.
// NEW this round: partial O written as FP16 (halves staging traffic 33->17MB;
// r11 proved fp16-partial numerics; NCHUNK stays 4 so epilogue count and
// norm_sum gather geometry are unchanged).
#define KT 64
template <bool STAGED>
__global__ __launch_bounds__(256) void flash_kernel(const _Float16* __restrict__ Qh,
                                                    const _Float16* __restrict__ Kh,
                                                    const _Float16* __restrict__ Vt,
                                                    float* __restrict__ outp,     // fallback
                                                    _Float16* __restrict__ outh,  // staged
                                                    float* __restrict__ lp) {
    __shared__ _Float16 Ks[2][KT * 64];       // [64][8 chunks of 8 halves], swizzled
    __shared__ _Float16 Vs[2][128 * 64];      // [128][8 chunks], swizzled

    const int t = threadIdx.x;
    const int qt = blockIdx.x, chunk = blockIdx.y, b = blockIdx.z;
    const int w = t >> 6, lane = t & 63, quad = lane >> 4, n16 = lane & 15;
    const int swz = n16 & 7;

    const size_t qrowA = (size_t)b * S_LEN + qt * 128 + w * 16 + n16;
    const size_t qrowB = qrowA + 64;
    half8 aQ0A = *(const half8*)&Qh[qrowA * 64 + quad * 8];
    half8 aQ1A = *(const half8*)&Qh[qrowA * 64 + 32 + quad * 8];
    half8 aQ0B = *(const half8*)&Qh[qrowB * 64 + quad * 8];
    half8 aQ1B = *(const half8*)&Qh[qrowB * 64 + 32 + quad * 8];

    half8 vones;
#pragma unroll
    for (int j = 0; j < 8; ++j) vones[j] = (_Float16)1.0f;

    float4v OA[8], OB[8];
#pragma unroll
    for (int vb = 0; vb < 8; ++vb) {
        OA[vb] = (float4v){0.f, 0.f, 0.f, 0.f};
        OB[vb] = (float4v){0.f, 0.f, 0.f, 0.f};
    }
    float4v accLA = (float4v){0.f, 0.f, 0.f, 0.f};   // l[q=quad*4+r], repl. over n16
    float4v accLB = (float4v){0.f, 0.f, 0.f, 0.f};

    const _Float16* Kb = Kh + (size_t)b * S_LEN * 64;
    const _Float16* Vb = Vt + (size_t)b * 128 * S_LEN;

    const int kt0 = chunk * (S_LEN / KT / NCHUNK);
    const int kt1 = kt0 + (S_LEN / KT / NCHUNK);

    // ---- async staging of tile kt into buffer bb (6 DMA loads/thread) ----
#define STAGE(bb, ktv) do {                                                    \
        const _Float16* Ksrc = Kb + (size_t)(ktv) * KT * 64;                   \
        _Float16* Kdst = &Ks[bb][0];                                           \
        _Float16* Vdst = &Vs[bb][0];                                           \
        for (int i_ = 0; i_ < 2; ++i_) {                                       \
            int d_ = t + i_ * 256, row_ = d_ >> 3, ch_ = d_ & 7;               \
            gload16(Ksrc + row_ * 64 + ((ch_ ^ (row_ & 7)) << 3), Kdst + d_ * 8); \
        }                                                                      \
        for (int i_ = 0; i_ < 4; ++i_) {                                       \
            int d_ = t + i_ * 256, row_ = d_ >> 3, ch_ = d_ & 7;               \
            gload16(Vb + (size_t)row_ * S_LEN + (ktv) * KT + ((ch_ ^ (row_ & 7)) << 3), \
                    Vdst + d_ * 8);                                            \
        }                                                                      \
    } while (0)

    // -------- prologue: DMA tile kt0 into buf0 --------
    STAGE(0, kt0);
    asm volatile("s_waitcnt vmcnt(0)" ::: "memory");
    __builtin_amdgcn_s_barrier();

    int cur = 0;
    for (int kt = kt0; kt < kt1; ++kt) {
        // issue next tile's DMA into the other buffer; lands during compute
        if (kt + 1 < kt1) STAGE(cur ^ 1, kt + 1);

        const _Float16* Ksc = Ks[cur];
        const _Float16* Vsc = Vs[cur];

        // -------- QK^T (swapped) + softmax; P packed into A-fragments --------
        half8 aP0A, aP1A, aP0B, aP1B;
        __builtin_amdgcn_s_setprio(1);
#pragma unroll
        for (int nb = 0; nb < 4; ++nb) {
            const int krow = (nb * 16 + n16) * 64;
            half8 bK0 = *(const half8*)&Ksc[krow + ((quad ^ swz) << 3)];
            half8 bK1 = *(const half8*)&Ksc[krow + (((4 + quad) ^ swz) << 3)];
            float4v scA = (float4v){0.f, 0.f, 0.f, 0.f};
            float4v scB = (float4v){0.f, 0.f, 0.f, 0.f};
            scA = __builtin_amdgcn_mfma_f32_16x16x32_f16(bK0, aQ0A, scA, 0, 0, 0);
            scA = __builtin_amdgcn_mfma_f32_16x16x32_f16(bK1, aQ1A, scA, 0, 0, 0);
            scB = __builtin_amdgcn_mfma_f32_16x16x32_f16(bK0, aQ0B, scB, 0, 0, 0);
            scB = __builtin_amdgcn_mfma_f32_16x16x32_f16(bK1, aQ1B, scB, 0, 0, 0);

            // Q pre-scaled by 0.125*log2e -> p = exp2(sc); shift cancels in O/l.
            // Pack pairs with v_cvt_pkrtz (one instr per 2 values).
            fp16x2 a01 = __builtin_amdgcn_cvt_pkrtz(
                __builtin_amdgcn_exp2f(scA[0]), __builtin_amdgcn_exp2f(scA[1]));
            fp16x2 a23 = __builtin_amdgcn_cvt_pkrtz(
                __builtin_amdgcn_exp2f(scA[2]), __builtin_amdgcn_exp2f(scA[3]));
            fp16x2 b01 = __builtin_amdgcn_cvt_pkrtz(
                __builtin_amdgcn_exp2f(scB[0]), __builtin_amdgcn_exp2f(scB[1]));
            fp16x2 b23 = __builtin_amdgcn_cvt_pkrtz(
                __builtin_amdgcn_exp2f(scB[2]), __builtin_amdgcn_exp2f(scB[3]));
            const int s = (nb & 1) * 4;
            if (nb < 2) {
                aP0A[s] = (_Float16)a01[0]; aP0A[s + 1] = (_Float16)a01[1];
                aP0A[s + 2] = (_Float16)a23[0]; aP0A[s + 3] = (_Float16)a23[1];
                aP0B[s] = (_Float16)b01[0]; aP0B[s + 1] = (_Float16)b01[1];
                aP0B[s + 2] = (_Float16)b23[0]; aP0B[s + 3] = (_Float16)b23[1];
            } else {
                aP1A[s] = (_Float16)a01[0]; aP1A[s + 1] = (_Float16)a01[1];
                aP1A[s + 2] = (_Float16)a23[0]; aP1A[s + 3] = (_Float16)a23[1];
                aP1B[s] = (_Float16)b01[0]; aP1B[s + 1] = (_Float16)b01[1];
                aP1B[s + 2] = (_Float16)b23[0]; aP1B[s + 3] = (_Float16)b23[1];
            }
        }
        // row-sums l[q] += sum_k P[q][k] via ones-MFMA (replaces 32 v_add)
        accLA = __builtin_amdgcn_mfma_f32_16x16x32_f16(aP0A, vones, accLA, 0, 0, 0);
        accLA = __builtin_amdgcn_mfma_f32_16x16x32_f16(aP1A, vones, accLA, 0, 0, 0);
        accLB = __builtin_amdgcn_mfma_f32_16x16x32_f16(aP0B, vones, accLB, 0, 0, 0);
        accLB = __builtin_amdgcn_mfma_f32_16x16x32_f16(aP1B, vones, accLB, 0, 0, 0);
        __builtin_amdgcn_s_setprio(0);

        // -------- PV: V frags contiguous b128 (permuted Vt + read swizzle) ----
        __builtin_amdgcn_s_setprio(1);
#pragma unroll
        for (int vb = 0; vb < 8; ++vb) {
            const int vrow = (vb * 16 + n16) * 64;
            half8 bV0 = *(const half8*)&Vsc[vrow + ((quad ^ swz) << 3)];
            half8 bV1 = *(const half8*)&Vsc[vrow + (((4 + quad) ^ swz) << 3)];
            OA[vb] = __builtin_amdgcn_mfma_f32_16x16x32_f16(aP0A, bV0, OA[vb], 0, 0, 0);
            OA[vb] = __builtin_amdgcn_mfma_f32_16x16x32_f16(aP1A, bV1, OA[vb], 0, 0, 0);
            OB[vb] = __builtin_amdgcn_mfma_f32_16x16x32_f16(aP0B, bV0, OB[vb], 0, 0, 0);
            OB[vb] = __builtin_amdgcn_mfma_f32_16x16x32_f16(aP1B, bV1, OB[vb], 0, 0, 0);
        }
        __builtin_amdgcn_s_setprio(0);

        if (kt + 1 < kt1) {
            // next buffer's DMA (issued a full body ago) must be complete in
            // ALL waves before anyone reads it.
            asm volatile("s_waitcnt vmcnt(0)" ::: "memory");
            __builtin_amdgcn_s_barrier();
            cur ^= 1;
        }
    }
#undef STAGE

    // accL layout: lane (quad,n16) reg r = l[quad*4+r], replicated over n16.
    const int rowbaseA = qt * 128 + w * 16;                 // within batch
    const int rowbaseB = rowbaseA + 64;
    const int row0A = rowbaseA + quad * 4;
    const int row0B = rowbaseB + quad * 4;

    if (STAGED) {
        // plain streaming stores into this chunk's private slice (O in fp16)
        const size_t cb = (size_t)chunk * NBATCH + b;
        if (n16 == 0)
#pragma unroll
            for (int r = 0; r < 4; ++r) {
                lp[cb * S_LEN + row0A + r] = accLA[r];
                lp[cb * S_LEN + row0B + r] = accLB[r];
            }
        _Float16* obA = outh + (cb * S_LEN + row0A) * 128;
        _Float16* obB = outh + (cb * S_LEN + row0B) * 128;
#pragma unroll
        for (int vb = 0; vb < 8; ++vb)
#pragma unroll
            for (int r = 0; r < 4; ++r) {
                obA[(size_t)r * 128 + vb * 16 + n16] = (_Float16)OA[vb][r];
                obB[(size_t)r * 128 + vb * 16 + n16] = (_Float16)OB[vb][r];
            }
    } else {
        if (n16 == 0)
#pragma unroll
            for (int r = 0; r < 4; ++r) {
                unsafeAtomicAdd(&lp[b * S_LEN + row0A + r], accLA[r]);
                unsafeAtomicAdd(&lp[b * S_LEN + row0B + r], accLB[r]);
            }
        float* obA = outp + ((size_t)b * S_LEN + row0A) * 128;
        float* obB = outp + ((size_t)b * S_LEN + row0B) * 128;
#pragma unroll
        for (int vb = 0; vb < 8; ++vb)
#pragma unroll
            for (int r = 0; r < 4; ++r) {
                unsafeAtomicAdd(&obA[(size_t)r * 128 + vb * 16 + n16], OA[vb][r]);
                unsafeAtomicAdd(&obB[(size_t)r * 128 + vb * 16 + n16], OB[vb][r]);
            }
    }
}

// ---------------- kernel 3a (STAGED): reduce fp16 chunk partials + normalize --
__global__ __launch_bounds__(256) void norm_sum_kernel(const _Float16* __restrict__ oaccH,
                                                       const float* __restrict__ lacc,
                                                       float4v* __restrict__ out4) {
    int i = blockIdx.x * 256 + threadIdx.x;   // 0..524287 (each = 4 output floats)
    int row = i >> 5;                         // global row: b*4096 + r
    float l = 0.f;
#pragma unroll
    for (int c = 0; c < NCHUNK; ++c) l += lacc[c * (NBATCH * S_LEN) + row];
    float4v s = (float4v){0.f, 0.f, 0.f, 0.f};
#pragma unroll
    for (int c = 0; c < NCHUNK; ++c) {
        half4v p = *(const half4v*)&oaccH[(size_t)c * CHUNK_ELEMS + (size_t)i * 4];
        s[0] += (float)p[0]; s[1] += (float)p[1];
        s[2] += (float)p[2]; s[3] += (float)p[3];
    }
    float inv = 1.0f / l;
    s[0] *= inv; s[1] *= inv; s[2] *= inv; s[3] *= inv;
    out4[i] = s;
}

// ---------------- kernel 3b (FALLBACK): normalize out in place ----------------
__global__ __launch_bounds__(256) void norm_kernel(float4v* __restrict__ out4,
                                                   const float* __restrict__ lbuf) {
    int i = blockIdx.x * 256 + threadIdx.x;   // 0..524287
    float inv = 1.0f / lbuf[i >> 5];
    float4v v = out4[i];
    v[0] *= inv; v[1] *= inv; v[2] *= inv; v[3] *= inv;
    out4[i] = v;
}

// ---------------- launch ------------------------------------------------------
extern "C" void kernel_launch(void* const* d_in, const int* in_sizes, int n_in,
                              void* d_out, int out_size, void* d_ws, size_t ws_size,
                              hipStream_t stream) {
    const float* x  = (const float*)d_in[0];
    const float* Wq = (const float*)d_in[1];
    const float* Wk = (const float*)d_in[2];
    const float* Wv = (const float*)d_in[3];
    float* out = (float*)d_out;

    _Float16* ws = (_Float16*)d_ws;
    _Float16* w16 = ws + WS_W16;
    _Float16* Qh  = ws + WS_QH;
    _Float16* Kh  = ws + WS_KH;
    _Float16* Vt  = ws + WS_VT;
    float*    lbuf = (float*)(ws + WS_L);

    wcvt_kernel<<<128, 256, 0, stream>>>(Wq, Wk, Wv, w16);
    qkv_proj_kernel<<<NBATCH * S_LEN / 16, 256, 0, stream>>>(x, w16, Qh, Kh, Vt);

    if (ws_size >= (size_t)WS_NEED_BYTES) {
        _Float16* oacc = (_Float16*)((char*)d_ws + OACC_BYTE_OFF);
        float*    lacc = (float*)((char*)d_ws + LACC_BYTE_OFF);
        flash_kernel<true><<<dim3(S_LEN / 128, NCHUNK, NBATCH), 256, 0, stream>>>(
            Qh, Kh, Vt, nullptr, oacc, lacc);
        norm_sum_kernel<<<2048, 256, 0, stream>>>(oacc, lacc, (float4v*)out);
    } else {
        zero_kernel<<<2048, 256, 0, stream>>>((float4v*)out, (float4v*)lbuf);
        flash_kernel<false><<<dim3(S_LEN / 128, NCHUNK, NBATCH), 256, 0, stream>>>(
            Qh, Kh, Vt, out, nullptr, lbuf);
        norm_kernel<<<2048, 256, 0, stream>>>((float4v*)out, lbuf);
    }
}

// Round 15
// 116.084 us; speedup vs baseline: 1.0279x; 1.0279x over previous
//
#include <hip/hip_runtime.h>

typedef _Float16 half8 __attribute__((ext_vector_type(8)));
typedef _Float16 half4v __attribute__((ext_vector_type(4)));
typedef __fp16  fp16x2 __attribute__((ext_vector_type(2)));   // cvt_pkrtz native type
typedef float   float4v __attribute__((ext_vector_type(4)));

#define S_LEN 4096
#define NBATCH 4
#define NCHUNK 4          // K-split factor: each chunk covers S/NCHUNK keys
// ws layout in halves:
//   W16  @ 0        : 256*128      = 32768
//   Qh   @ 32768    : 16384*64     = 1048576   (token-major [B*S][64], PRE-SCALED
//                     by 0.125*log2e so softmax is p = exp2(sc) with no fma)
//   Kh   @ 1081344  : 16384*64     = 1048576
//   Vt   @ 2129920  : 4*128*4096   = 2097152   (per-batch [128][S], PERMUTED per
//                     64-key tile: key k=grp*32+g*16+q*4+r stored at grp*32+q*8+g*4+r)
//   L    @ 4227072  : 16384 floats (fallback path accumulators)
// staged-path extras (byte offsets from ws base):
//   OACC @ 8519680  : NCHUNK*4*4096*128 fp32 = 32 MB   (per-chunk partial O)
//   LACC @ 42074112 : NCHUNK*4*4096 fp32     = 256 KB  (per-chunk partial l)
#define WS_W16 0
#define WS_QH  32768
#define WS_KH  1081344
#define WS_VT  2129920
#define WS_L   4227072
#define OACC_BYTE_OFF 8519680ull
#define OACC_F4_PER_CHUNK (NBATCH * S_LEN * 128 / 4)            // 524288
#define LACC_BYTE_OFF (OACC_BYTE_OFF + (unsigned long long)NCHUNK * NBATCH * S_LEN * 128 * 4)
#define WS_NEED_BYTES (LACC_BYTE_OFF + (unsigned long long)NCHUNK * NBATCH * S_LEN * 4)

#define QSCALE 0.18033688011112042f   // 0.125 * log2(e)

// async global -> LDS, 16 bytes per lane (global_load_lds_dwordx4)
static __device__ __forceinline__ void gload16(const _Float16* g, _Float16* l) {
    __builtin_amdgcn_global_load_lds(
        (const __attribute__((address_space(1))) void*)g,
        (__attribute__((address_space(3))) void*)l, 16, 0, 0);
}

// ---------------- kernel 0a: convert weights fp32 -> fp16, packed [256][128] --
__global__ __launch_bounds__(256) void wcvt_kernel(const float* __restrict__ Wq,
                                                   const float* __restrict__ Wk,
                                                   const float* __restrict__ Wv,
                                                   _Float16* __restrict__ w16) {
    int i = blockIdx.x * 256 + threadIdx.x;   // 0..32767
    int row = i >> 7, col = i & 127;
    float v;
    if (row < 64)       v = Wq[row * 128 + col];
    else if (row < 128) v = Wk[(row - 64) * 128 + col];
    else                v = Wv[(row - 128) * 128 + col];
    w16[i] = (_Float16)v;
}

// ---------------- kernel 0b (FALLBACK only): zero out + lbuf ------------------
__global__ __launch_bounds__(256) void zero_kernel(float4v* __restrict__ out4,
                                                   float4v* __restrict__ l4) {
    int i = blockIdx.x * 256 + threadIdx.x;   // 0..524287
    out4[i] = (float4v){0.f, 0.f, 0.f, 0.f};
    if (i < 4096) l4[i] = (float4v){0.f, 0.f, 0.f, 0.f};
}

// ---------------- kernel 1: QKV projection via MFMA (r7-proven form) ----------
// grid 1024 blocks x 256 thr; block owns 16 tokens; wave w owns oc [w*64, +64):
//   wave 0 -> Q (pre-scaled by QSCALE), wave 1 -> K, waves 2,3 -> V.
__global__ __launch_bounds__(256) void qkv_proj_kernel(const float* __restrict__ x,
                                                       const _Float16* __restrict__ w16,
                                                       _Float16* __restrict__ Qh,
                                                       _Float16* __restrict__ Kh,
                                                       _Float16* __restrict__ Vt) {
    __shared__ _Float16 xs[16 * 136];   // 16 rows, stride 136 halves (pad 128->136)
    const int t = threadIdx.x;
    const int blk = blockIdx.x;
    const float* xb = x + (size_t)blk * 16 * 128;

    for (int it = 0; it < 2; ++it) {
        int i = t + it * 256;           // 0..511 float4
        int row = i >> 5, c4 = i & 31;
        float4v f = ((const float4v*)xb)[i];
        half4v h;
        h[0] = (_Float16)f[0]; h[1] = (_Float16)f[1];
        h[2] = (_Float16)f[2]; h[3] = (_Float16)f[3];
        *(half4v*)&xs[row * 136 + c4 * 4] = h;
    }
    __syncthreads();

    const int w = t >> 6, lane = t & 63, quad = lane >> 4, n16 = lane & 15;

    half8 a[4];
    for (int c = 0; c < 4; ++c)
        a[c] = *(const half8*)&xs[n16 * 136 + c * 32 + quad * 8];

    float4v acc[4];
    for (int nb = 0; nb < 4; ++nb) acc[nb] = (float4v){0.f, 0.f, 0.f, 0.f};

    for (int c = 0; c < 4; ++c) {
        for (int nb = 0; nb < 4; ++nb) {
            int oc = w * 64 + nb * 16 + n16;
            half8 bfr = *(const half8*)&w16[(size_t)oc * 128 + c * 32 + quad * 8];
            acc[nb] = __builtin_amdgcn_mfma_f32_16x16x32_f16(a[c], bfr, acc[nb], 0, 0, 0);
        }
    }

    const int token0 = blk * 16 + quad * 4;
    if (w == 0) {
        // Q pre-scaled: softmax in flash becomes p = exp2(sc), no fma/shift.
        // (The dropped shift constant cancels exactly in the O/l normalization.)
        for (int nb = 0; nb < 4; ++nb)
            for (int r = 0; r < 4; ++r)
                Qh[(size_t)(token0 + r) * 64 + nb * 16 + n16] =
                    (_Float16)(acc[nb][r] * QSCALE);
    } else if (w == 1) {
        for (int nb = 0; nb < 4; ++nb)
            for (int r = 0; r < 4; ++r)
                Kh[(size_t)(token0 + r) * 64 + nb * 16 + n16] = (_Float16)acc[nb][r];
    } else {
        // V store, PERMUTED within each 64-key tile so flash reads b128 frags:
        // key s = kt*64+grp*32+g*16+q*4+r  ->  pos = kt*64+grp*32+q*8+g*4+r
        const int bb = token0 >> 12, s0 = token0 & 4095;
        const int kt = s0 >> 6, k0 = s0 & 63;
        const int grp = k0 >> 5, k32 = k0 & 31;
        const int g = k32 >> 4, q = (k32 >> 2) & 3;
        const int off = kt * 64 + grp * 32 + q * 8 + g * 4;
        for (int nb = 0; nb < 4; ++nb) {
            const int vc = (w - 2) * 64 + nb * 16 + n16;
            half4v h;
            h[0] = (_Float16)acc[nb][0]; h[1] = (_Float16)acc[nb][1];
            h[2] = (_Float16)acc[nb][2]; h[3] = (_Float16)acc[nb][3];
            *(half4v*)&Vt[((size_t)bb * 128 + vc) * S_LEN + off] = h;
        }
    }
}

// ---------------- kernel 2: flash attention, K-split x4, 2 q-tiles/wave -------
// grid (S/128, NCHUNK, B), 256 threads.  Best-measured structure (r13, 116.4us):
// double-buffered LDS via global_load_lds DMA (linear dest, source pre-swizzle
// LDS(row,ch) <- global(row, ch^(row&7))); ONE vmcnt(0)+barrier per iteration;
// 0 bank conflicts; setprio around MFMA clusters; p = exp2(sc) (Q pre-scaled,
// shift cancels in O/l); row-sums via ones-MFMA; P -> f16 via v_cvt_pkrtz.
// Staged split-K epilogue: fp32 partials, plain streaming stores (no atomic
// RMW at HBM -- the r7 lever, -15us); norm_sum reduces and normalizes.
#define KT 64
template <bool STAGED>
__global__ __launch_bounds__(256) void flash_kernel(const _Float16* __restrict__ Qh,
                                                    const _Float16* __restrict__ Kh,
                                                    const _Float16* __restrict__ Vt,
                                                    float* __restrict__ outp,
                                                    float* __restrict__ lp) {
    __shared__ _Float16 Ks[2][KT * 64];       // [64][8 chunks of 8 halves], swizzled
    __shared__ _Float16 Vs[2][128 * 64];      // [128][8 chunks], swizzled

    const int t = threadIdx.x;
    const int qt = blockIdx.x, chunk = blockIdx.y, b = blockIdx.z;
    const int w = t >> 6, lane = t & 63, quad = lane >> 4, n16 = lane & 15;
    const int swz = n16 & 7;

    const size_t qrowA = (size_t)b * S_LEN + qt * 128 + w * 16 + n16;
    const size_t qrowB = qrowA + 64;
    half8 aQ0A = *(const half8*)&Qh[qrowA * 64 + quad * 8];
    half8 aQ1A = *(const half8*)&Qh[qrowA * 64 + 32 + quad * 8];
    half8 aQ0B = *(const half8*)&Qh[qrowB * 64 + quad * 8];
    half8 aQ1B = *(const half8*)&Qh[qrowB * 64 + 32 + quad * 8];

    half8 vones;
#pragma unroll
    for (int j = 0; j < 8; ++j) vones[j] = (_Float16)1.0f;

    float4v OA[8], OB[8];
#pragma unroll
    for (int vb = 0; vb < 8; ++vb) {
        OA[vb] = (float4v){0.f, 0.f, 0.f, 0.f};
        OB[vb] = (float4v){0.f, 0.f, 0.f, 0.f};
    }
    float4v accLA = (float4v){0.f, 0.f, 0.f, 0.f};   // l[q=quad*4+r], repl. over n16
    float4v accLB = (float4v){0.f, 0.f, 0.f, 0.f};

    const _Float16* Kb = Kh + (size_t)b * S_LEN * 64;
    const _Float16* Vb = Vt + (size_t)b * 128 * S_LEN;

    const int kt0 = chunk * (S_LEN / KT / NCHUNK);
    const int kt1 = kt0 + (S_LEN / KT / NCHUNK);

    // ---- async staging of tile kt into buffer bb (6 DMA loads/thread) ----
#define STAGE(bb, ktv) do {                                                    \
        const _Float16* Ksrc = Kb + (size_t)(ktv) * KT * 64;                   \
        _Float16* Kdst = &Ks[bb][0];                                           \
        _Float16* Vdst = &Vs[bb][0];                                           \
        for (int i_ = 0; i_ < 2; ++i_) {                                       \
            int d_ = t + i_ * 256, row_ = d_ >> 3, ch_ = d_ & 7;               \
            gload16(Ksrc + row_ * 64 + ((ch_ ^ (row_ & 7)) << 3), Kdst + d_ * 8); \
        }                                                                      \
        for (int i_ = 0; i_ < 4; ++i_) {                                       \
            int d_ = t + i_ * 256, row_ = d_ >> 3, ch_ = d_ & 7;               \
            gload16(Vb + (size_t)row_ * S_LEN + (ktv) * KT + ((ch_ ^ (row_ & 7)) << 3), \
                    Vdst + d_ * 8);                                            \
        }                                                                      \
    } while (0)

    // -------- prologue: DMA tile kt0 into buf0 --------
    STAGE(0, kt0);
    asm volatile("s_waitcnt vmcnt(0)" ::: "memory");
    __builtin_amdgcn_s_barrier();

    int cur = 0;
    for (int kt = kt0; kt < kt1; ++kt) {
        // issue next tile's DMA into the other buffer; lands during compute
        if (kt + 1 < kt1) STAGE(cur ^ 1, kt + 1);

        const _Float16* Ksc = Ks[cur];
        const _Float16* Vsc = Vs[cur];

        // -------- QK^T (swapped) + softmax; P packed into A-fragments --------
        half8 aP0A, aP1A, aP0B, aP1B;
        __builtin_amdgcn_s_setprio(1);
#pragma unroll
        for (int nb = 0; nb < 4; ++nb) {
            const int krow = (nb * 16 + n16) * 64;
            half8 bK0 = *(const half8*)&Ksc[krow + ((quad ^ swz) << 3)];
            half8 bK1 = *(const half8*)&Ksc[krow + (((4 + quad) ^ swz) << 3)];
            float4v scA = (float4v){0.f, 0.f, 0.f, 0.f};
            float4v scB = (float4v){0.f, 0.f, 0.f, 0.f};
            scA = __builtin_amdgcn_mfma_f32_16x16x32_f16(bK0, aQ0A, scA, 0, 0, 0);
            scA = __builtin_amdgcn_mfma_f32_16x16x32_f16(bK1, aQ1A, scA, 0, 0, 0);
            scB = __builtin_amdgcn_mfma_f32_16x16x32_f16(bK0, aQ0B, scB, 0, 0, 0);
            scB = __builtin_amdgcn_mfma_f32_16x16x32_f16(bK1, aQ1B, scB, 0, 0, 0);

            // Q pre-scaled by 0.125*log2e -> p = exp2(sc); shift cancels in O/l.
            // Pack pairs with v_cvt_pkrtz (one instr per 2 values).
            fp16x2 a01 = __builtin_amdgcn_cvt_pkrtz(
                __builtin_amdgcn_exp2f(scA[0]), __builtin_amdgcn_exp2f(scA[1]));
            fp16x2 a23 = __builtin_amdgcn_cvt_pkrtz(
                __builtin_amdgcn_exp2f(scA[2]), __builtin_amdgcn_exp2f(scA[3]));
            fp16x2 b01 = __builtin_amdgcn_cvt_pkrtz(
                __builtin_amdgcn_exp2f(scB[0]), __builtin_amdgcn_exp2f(scB[1]));
            fp16x2 b23 = __builtin_amdgcn_cvt_pkrtz(
                __builtin_amdgcn_exp2f(scB[2]), __builtin_amdgcn_exp2f(scB[3]));
            const int s = (nb & 1) * 4;
            if (nb < 2) {
                aP0A[s] = (_Float16)a01[0]; aP0A[s + 1] = (_Float16)a01[1];
                aP0A[s + 2] = (_Float16)a23[0]; aP0A[s + 3] = (_Float16)a23[1];
                aP0B[s] = (_Float16)b01[0]; aP0B[s + 1] = (_Float16)b01[1];
                aP0B[s + 2] = (_Float16)b23[0]; aP0B[s + 3] = (_Float16)b23[1];
            } else {
                aP1A[s] = (_Float16)a01[0]; aP1A[s + 1] = (_Float16)a01[1];
                aP1A[s + 2] = (_Float16)a23[0]; aP1A[s + 3] = (_Float16)a23[1];
                aP1B[s] = (_Float16)b01[0]; aP1B[s + 1] = (_Float16)b01[1];
                aP1B[s + 2] = (_Float16)b23[0]; aP1B[s + 3] = (_Float16)b23[1];
            }
        }
        // row-sums l[q] += sum_k P[q][k] via ones-MFMA (replaces 32 v_add)
        accLA = __builtin_amdgcn_mfma_f32_16x16x32_f16(aP0A, vones, accLA, 0, 0, 0);
        accLA = __builtin_amdgcn_mfma_f32_16x16x32_f16(aP1A, vones, accLA, 0, 0, 0);
        accLB = __builtin_amdgcn_mfma_f32_16x16x32_f16(aP0B, vones, accLB, 0, 0, 0);
        accLB = __builtin_amdgcn_mfma_f32_16x16x32_f16(aP1B, vones, accLB, 0, 0, 0);
        __builtin_amdgcn_s_setprio(0);

        // -------- PV: V frags contiguous b128 (permuted Vt + read swizzle) ----
        __builtin_amdgcn_s_setprio(1);
#pragma unroll
        for (int vb = 0; vb < 8; ++vb) {
            const int vrow = (vb * 16 + n16) * 64;
            half8 bV0 = *(const half8*)&Vsc[vrow + ((quad ^ swz) << 3)];
            half8 bV1 = *(const half8*)&Vsc[vrow + (((4 + quad) ^ swz) << 3)];
            OA[vb] = __builtin_amdgcn_mfma_f32_16x16x32_f16(aP0A, bV0, OA[vb], 0, 0, 0);
            OA[vb] = __builtin_amdgcn_mfma_f32_16x16x32_f16(aP1A, bV1, OA[vb], 0, 0, 0);
            OB[vb] = __builtin_amdgcn_mfma_f32_16x16x32_f16(aP0B, bV0, OB[vb], 0, 0, 0);
            OB[vb] = __builtin_amdgcn_mfma_f32_16x16x32_f16(aP1B, bV1, OB[vb], 0, 0, 0);
        }
        __builtin_amdgcn_s_setprio(0);

        if (kt + 1 < kt1) {
            // next buffer's DMA (issued a full body ago) must be complete in
            // ALL waves before anyone reads it.
            asm volatile("s_waitcnt vmcnt(0)" ::: "memory");
            __builtin_amdgcn_s_barrier();
            cur ^= 1;
        }
    }
#undef STAGE

    // accL layout: lane (quad,n16) reg r = l[quad*4+r], replicated over n16.
    const int rowbaseA = qt * 128 + w * 16;                 // within batch
    const int rowbaseB = rowbaseA + 64;
    const int row0A = rowbaseA + quad * 4;
    const int row0B = rowbaseB + quad * 4;

    if (STAGED) {
        // plain streaming stores into this chunk's private slice
        const size_t cb = (size_t)chunk * NBATCH + b;
        if (n16 == 0)
#pragma unroll
            for (int r = 0; r < 4; ++r) {
                lp[cb * S_LEN + row0A + r] = accLA[r];
                lp[cb * S_LEN + row0B + r] = accLB[r];
            }
        float* obA = outp + (cb * S_LEN + row0A) * 128;
        float* obB = outp + (cb * S_LEN + row0B) * 128;
#pragma unroll
        for (int vb = 0; vb < 8; ++vb)
#pragma unroll
            for (int r = 0; r < 4; ++r) {
                obA[(size_t)r * 128 + vb * 16 + n16] = OA[vb][r];
                obB[(size_t)r * 128 + vb * 16 + n16] = OB[vb][r];
            }
    } else {
        if (n16 == 0)
#pragma unroll
            for (int r = 0; r < 4; ++r) {
                unsafeAtomicAdd(&lp[b * S_LEN + row0A + r], accLA[r]);
                unsafeAtomicAdd(&lp[b * S_LEN + row0B + r], accLB[r]);
            }
        float* obA = outp + ((size_t)b * S_LEN + row0A) * 128;
        float* obB = outp + ((size_t)b * S_LEN + row0B) * 128;
#pragma unroll
        for (int vb = 0; vb < 8; ++vb)
#pragma unroll
            for (int r = 0; r < 4; ++r) {
                unsafeAtomicAdd(&obA[(size_t)r * 128 + vb * 16 + n16], OA[vb][r]);
                unsafeAtomicAdd(&obB[(size_t)r * 128 + vb * 16 + n16], OB[vb][r]);
            }
    }
}

// ---------------- kernel 3a (STAGED): reduce chunk partials + normalize -------
__global__ __launch_bounds__(256) void norm_sum_kernel(const float4v* __restrict__ oacc4,
                                                       const float* __restrict__ lacc,
                                                       float4v* __restrict__ out4) {
    int i = blockIdx.x * 256 + threadIdx.x;   // 0..524287 (32 float4 per row)
    int row = i >> 5;                         // global row: b*4096 + r
    float l = 0.f;
#pragma unroll
    for (int c = 0; c < NCHUNK; ++c) l += lacc[c * (NBATCH * S_LEN) + row];
    float4v s = (float4v){0.f, 0.f, 0.f, 0.f};
#pragma unroll
    for (int c = 0; c < NCHUNK; ++c) {
        float4v p = oacc4[(size_t)c * OACC_F4_PER_CHUNK + i];
        s[0] += p[0]; s[1] += p[1]; s[2] += p[2]; s[3] += p[3];
    }
    float inv = 1.0f / l;
    s[0] *= inv; s[1] *= inv; s[2] *= inv; s[3] *= inv;
    out4[i] = s;
}

// ---------------- kernel 3b (FALLBACK): normalize out in place ----------------
__global__ __launch_bounds__(256) void norm_kernel(float4v* __restrict__ out4,
                                                   const float* __restrict__ lbuf) {
    int i = blockIdx.x * 256 + threadIdx.x;   // 0..524287
    float inv = 1.0f / lbuf[i >> 5];
    float4v v = out4[i];
    v[0] *= inv; v[1] *= inv; v[2] *= inv; v[3] *= inv;
    out4[i] = v;
}

// ---------------- launch ------------------------------------------------------
extern "C" void kernel_launch(void* const* d_in, const int* in_sizes, int n_in,
                              void* d_out, int out_size, void* d_ws, size_t ws_size,
                              hipStream_t stream) {
    const float* x  = (const float*)d_in[0];
    const float* Wq = (const float*)d_in[1];
    const float* Wk = (const float*)d_in[2];
    const float* Wv = (const float*)d_in[3];
    float* out = (float*)d_out;

    _Float16* ws = (_Float16*)d_ws;
    _Float16* w16 = ws + WS_W16;
    _Float16* Qh  = ws + WS_QH;
    _Float16* Kh  = ws + WS_KH;
    _Float16* Vt  = ws + WS_VT;
    float*    lbuf = (float*)(ws + WS_L);

    wcvt_kernel<<<128, 256, 0, stream>>>(Wq, Wk, Wv, w16);
    qkv_proj_kernel<<<NBATCH * S_LEN / 16, 256, 0, stream>>>(x, w16, Qh, Kh, Vt);

    if (ws_size >= (size_t)WS_NEED_BYTES) {
        float* oacc = (float*)((char*)d_ws + OACC_BYTE_OFF);
        float* lacc = (float*)((char*)d_ws + LACC_BYTE_OFF);
        flash_kernel<true><<<dim3(S_LEN / 128, NCHUNK, NBATCH), 256, 0, stream>>>(
            Qh, Kh, Vt, oacc, lacc);
        norm_sum_kernel<<<2048, 256, 0, stream>>>((const float4v*)oacc, lacc, (float4v*)out);
    } else {
        zero_kernel<<<2048, 256, 0, stream>>>((float4v*)out, (float4v*)lbuf);
        flash_kernel<false><<<dim3(S_LEN / 128, NCHUNK, NBATCH), 256, 0, stream>>>(
            Qh, Kh, Vt, out, lbuf);
        norm_kernel<<<2048, 256, 0, stream>>>((float4v*)out, lbuf);
    }
}